// Round 9
// baseline (209.881 us; speedup 1.0000x reference)
//
#include <hip/hip_runtime.h>
#include <math.h>

#define H 64
#define W 64
#define C 256
#define O 256
#define CK 2304
#define NB 8
#define HWSZ 4096            // H*W

typedef __attribute__((ext_vector_type(8))) short short8;
typedef __attribute__((ext_vector_type(4))) float floatx4;
typedef __attribute__((ext_vector_type(4))) unsigned uintx4;

// swizzle giving uniform bank-group coverage in every 16-lane b128 phase
// for both the sampling-write map and the MFMA-read map
#define FSWZ(n) ((((n) & 3) << 1) | (((n) >> 2) & 1))

__device__ __forceinline__ float lo2f(unsigned u) {
  return __builtin_bit_cast(float, u << 16);
}
__device__ __forceinline__ float hi2f(unsigned u) {
  return __builtin_bit_cast(float, u & 0xffff0000u);
}
// pack two fp32 -> bf16 pair (low = v0, high = v1)
__device__ __forceinline__ unsigned pk2bf(float v0, float v1) {
  unsigned a = __builtin_bit_cast(unsigned, v0);
  unsigned b = __builtin_bit_cast(unsigned, v1);
  return ((a + 0x8000u) >> 16) | ((b + 0x8000u) & 0xffff0000u);
}
__device__ __forceinline__ unsigned cvtpk(float v0, float v1) {
#if defined(__gfx950__) && __has_builtin(__builtin_amdgcn_cvt_pk_bf16_f32)
  typedef __attribute__((ext_vector_type(2))) __bf16 bf16x2;
  bf16x2 t = __builtin_amdgcn_cvt_pk_bf16_f32(v0, v1);
  return __builtin_bit_cast(unsigned, t);
#else
  return pk2bf(v0, v1);
#endif
}

// ---------------- prep_all: transpose + weight packs + BN, ONE launch -----
__global__ __launch_bounds__(256) void prep_all(
    const float* __restrict__ x, const float* __restrict__ weight,
    const float* __restrict__ w_off, const float* __restrict__ bias,
    const float* __restrict__ gamma, const float* __restrict__ beta,
    const float* __restrict__ run_mean, const float* __restrict__ run_var,
    unsigned short* __restrict__ xt, unsigned short* __restrict__ wb,
    unsigned short* __restrict__ wob, float* __restrict__ invsh) {
  __shared__ unsigned tile[64 * 65];
  int bid = blockIdx.x;
  int tid = threadIdx.x;

  if (bid < 1024) {
    // ---- transpose: block = (b, y, cg-half of channels) ----
    int b = bid & 7;
    int t = bid >> 3;
    int y = t >> 1;
    int cg = t & 1;
    const float* xb = x + ((size_t)b * C + cg * 128) * HWSZ + y * W;
#pragma unroll
    for (int it = 0; it < 4; ++it) {
      int e = tid + 256 * it;              // (cp 0..63) x (xx4 0..15)
      int xx4 = e & 15;
      int cp = e >> 4;
      floatx4 f0 = *reinterpret_cast<const floatx4*>(
          xb + (size_t)(2 * cp) * HWSZ + xx4 * 4);
      floatx4 f1 = *reinterpret_cast<const floatx4*>(
          xb + (size_t)(2 * cp + 1) * HWSZ + xx4 * 4);
#pragma unroll
      for (int k = 0; k < 4; ++k)
        tile[cp * 65 + xx4 * 4 + k] = cvtpk(f0[k], f1[k]);
    }
    __syncthreads();
    unsigned short* xo = xt + ((size_t)(b * 64 + y) << 14) + cg * 128;
#pragma unroll
    for (int it = 0; it < 4; ++it) {
      int e = tid + 256 * it;
      int cq = e & 15;
      int xx = e >> 4;
      unsigned u0 = tile[(cq * 4 + 0) * 65 + xx];
      unsigned u1 = tile[(cq * 4 + 1) * 65 + xx];
      unsigned u2 = tile[(cq * 4 + 2) * 65 + xx];
      unsigned u3 = tile[(cq * 4 + 3) * 65 + xx];
      uint4 v = {u0, u1, u2, u3};
      *reinterpret_cast<uint4*>(xo + (xx << 8) + (cq << 3)) = v;
    }
  } else if (bid < 1312) {
    // ---- prep main weight: 8 elems/thread, one b128 store ----
    int d0 = ((bid - 1024) * 256 + tid) * 8;
    int lane = (d0 >> 3) & 63;
    int mt = (d0 >> 9) & 15;
    int ks = d0 >> 13;
    int o = mt * 16 + (lane & 15);
    int kn0 = ks * 32 + (lane >> 4) * 8;
    int tap = kn0 >> 8;
    int c0 = kn0 & 255;
    const float* wsrc = weight + o * CK + c0 * 9 + tap;
    unsigned pk[4];
#pragma unroll
    for (int p = 0; p < 4; ++p)
      pk[p] = cvtpk(wsrc[(2 * p) * 9], wsrc[(2 * p + 1) * 9]);
    uint4 v = {pk[0], pk[1], pk[2], pk[3]};
    *reinterpret_cast<uint4*>(wb + d0) = v;
  } else if (bid < 1348) {
    // ---- prep offset weight (M padded 27->32) ----
    int d0 = ((bid - 1312) * 256 + tid) * 8;
    int lane = (d0 >> 3) & 63;
    int mt = (d0 >> 9) & 1;
    int ks = d0 >> 10;
    int o = mt * 16 + (lane & 15);
    int kn0 = ks * 32 + (lane >> 4) * 8;
    int tap = kn0 >> 8;
    int c0 = kn0 & 255;
    uint4 v;
    if (o < 27) {
      const float* wsrc = w_off + o * CK + c0 * 9 + tap;
      unsigned pk[4];
#pragma unroll
      for (int p = 0; p < 4; ++p)
        pk[p] = cvtpk(wsrc[(2 * p) * 9], wsrc[(2 * p + 1) * 9]);
      v = (uint4){pk[0], pk[1], pk[2], pk[3]};
    } else {
      v = (uint4){0, 0, 0, 0};
    }
    *reinterpret_cast<uint4*>(wob + d0) = v;
  } else {
    // ---- folded BN ----
    int o = tid;
    float inv = gamma[o] * rsqrtf(run_var[o] + 1e-5f);
    invsh[o] = inv;
    invsh[O + o] = beta[o] + (bias[o] - run_mean[o]) * inv;
  }
}

// ---------------- Fused kernel: offset conv + deform sample + GEMM + BN ---
// grid (b, h), 512 threads (8 waves).  Block = row h: 64 px x 256 out.
__global__ __launch_bounds__(512, 4) void deform_mfma_kernel(
    const unsigned short* __restrict__ xt, const unsigned short* __restrict__ wob,
    const float* __restrict__ b_off, const unsigned short* __restrict__ wb,
    const float* __restrict__ invsh, float* __restrict__ out) {
  __shared__ short cols[64 * 256];       // 32 KB, FSWZ-swizzled
  __shared__ float sm_om[27 * 64];       // offset-conv result for this row
  __shared__ int sbase[576];
  __shared__ float s00[576], s01[576], s10[576], s11[576];

  int tid = threadIdx.x;
  int lane = tid & 63;
  int wvid = tid >> 6;                   // 0..7
  int q = lane >> 4;
  int lm = lane & 15;
  int b = blockIdx.x;
  int h = blockIdx.y;
  const unsigned short* xtb = xt + ((size_t)b << 20);

  // ======== Phase A: offset conv, 8 waves, wave = 1 mt x 1 nt
  {
    int mt = wvid & 1;
    int nt = wvid >> 1;                  // 0..3
    floatx4 a0 = (floatx4){0.f, 0.f, 0.f, 0.f};
    int px = nt * 16 + lm;
    for (int tap = 0; tap < 9; ++tap) {
      int yy = h - 1 + tap / 3;
      int xx = px - 1 + tap % 3;
      bool v = (yy >= 0) && (yy < H) && (xx >= 0) && (xx < W);
      const unsigned short* bp =
          xtb + ((((yy & 63) << 6) + (xx & 63)) << 8) + q * 8;
#pragma unroll
      for (int s = 0; s < 8; ++s) {
        int ks = tap * 8 + s;
        short8 bfrag;
        if (v)
          bfrag = *reinterpret_cast<const short8*>(bp + s * 32);
        else
          bfrag = (short8){0, 0, 0, 0, 0, 0, 0, 0};
        short8 afrag = *reinterpret_cast<const short8*>(
            wob + (((ks * 2 + mt) * 64 + lane) << 3));
        a0 = __builtin_amdgcn_mfma_f32_16x16x32_bf16(afrag, bfrag, a0, 0, 0, 0);
      }
    }
#pragma unroll
    for (int r = 0; r < 4; ++r) {
      int o = mt * 16 + q * 4 + r;
      if (o < 27) sm_om[o * 64 + px] = a0[r] + b_off[o];
    }
  }
  __syncthreads();

  // ======== Phase A2: separable clamp-swap bilinear tables (9 taps x 64 px)
  for (int e = tid; e < 576; e += 512) {
    int n = e & 63;
    int k = e >> 6;
    float oy = sm_om[k * 64 + n];
    float ox = sm_om[(9 + k) * 64 + n];
    float mv = sm_om[(18 + k) * 64 + n];
    float m = 1.0f / (1.0f + __expf(-mv));
    float py = (float)(h - 1 + k / 3) + oy;
    float px = (float)(n - 1 + k % 3) + ox;
    float yf = floorf(py), xf = floorf(px);
    int y0 = (int)yf, x0 = (int)xf;
    float fy = py - yf, fx = px - xf;
    float r0, r1; int yl;
    if (y0 >= 0 && y0 <= H - 2)      { yl = y0;    r0 = 1.f - fy; r1 = fy;       }
    else if (y0 == -1)               { yl = 0;     r0 = fy;       r1 = 0.f;      }
    else if (y0 == H - 1)            { yl = H - 2; r0 = 0.f;      r1 = 1.f - fy; }
    else                             { yl = 0;     r0 = 0.f;      r1 = 0.f;      }
    float c0, c1; int xl;
    if (x0 >= 0 && x0 <= W - 2)      { xl = x0;    c0 = 1.f - fx; c1 = fx;       }
    else if (x0 == -1)               { xl = 0;     c0 = fx;       c1 = 0.f;      }
    else if (x0 == W - 1)            { xl = W - 2; c0 = 0.f;      c1 = 1.f - fx; }
    else                             { xl = 0;     c0 = 0.f;      c1 = 0.f;      }
    r0 *= m; r1 *= m;
    sbase[e] = ((yl << 6) + xl) << 8;
    s00[e] = r0 * c0; s01[e] = r0 * c1;
    s10[e] = r1 * c0; s11[e] = r1 * c1;
  }
  __syncthreads();

  // ======== Phase B: main deformable GEMM, software-pipelined sampling
  floatx4 acc[2][4];                     // [m within pair][n-tile]
#pragma unroll
  for (int a = 0; a < 2; ++a)
#pragma unroll
    for (int u = 0; u < 4; ++u) acc[a][u] = (floatx4){0.f, 0.f, 0.f, 0.f};

  int sn = tid >> 3;        // pixel 0..63
  int scb = tid & 7;        // c-block low bits

  // prefetch registers: corners for i = 0,1 of the upcoming tap
  uintx4 pf00[2], pf01[2], pf10[2], pf11[2];
  {
    const unsigned short* p0 = xtb + sbase[sn];   // tap 0
#pragma unroll
    for (int i = 0; i < 2; ++i) {
      int co = ((i << 3) | scb) << 3;
      pf00[i] = *reinterpret_cast<const uintx4*>(p0 + co);
      pf01[i] = *reinterpret_cast<const uintx4*>(p0 + 256 + co);
      pf10[i] = *reinterpret_cast<const uintx4*>(p0 + 16384 + co);
      pf11[i] = *reinterpret_cast<const uintx4*>(p0 + 16640 + co);
    }
  }

  for (int tap = 0; tap < 9; ++tap) {
    int ei = tap * 64 + sn;
    float w00 = s00[ei], w01 = s01[ei], w10 = s10[ei], w11 = s11[ei];
    const unsigned short* p = xtb + sbase[ei];

    // issue the i = 2,3 corner loads first (latency hidden by i=0,1 pack)
    uintx4 t00[2], t01[2], t10[2], t11[2];
#pragma unroll
    for (int i = 0; i < 2; ++i) {
      int co = (((i + 2) << 3) | scb) << 3;
      t00[i] = *reinterpret_cast<const uintx4*>(p + co);
      t01[i] = *reinterpret_cast<const uintx4*>(p + 256 + co);
      t10[i] = *reinterpret_cast<const uintx4*>(p + 16384 + co);
      t11[i] = *reinterpret_cast<const uintx4*>(p + 16640 + co);
    }
    // pack + write i = 0,1 from prefetch regs
#pragma unroll
    for (int i = 0; i < 2; ++i) {
      int cbw = (i << 3) | scb;
      uintx4 res;
#pragma unroll
      for (int jd = 0; jd < 4; ++jd) {
        float v0 = fmaf(w00, lo2f(pf00[i][jd]),
                   fmaf(w01, lo2f(pf01[i][jd]),
                   fmaf(w10, lo2f(pf10[i][jd]), w11 * lo2f(pf11[i][jd]))));
        float v1 = fmaf(w00, hi2f(pf00[i][jd]),
                   fmaf(w01, hi2f(pf01[i][jd]),
                   fmaf(w10, hi2f(pf10[i][jd]), w11 * hi2f(pf11[i][jd]))));
        res[jd] = cvtpk(v0, v1);
      }
      int pos = (cbw ^ FSWZ(sn)) & 31;
      *reinterpret_cast<uintx4*>(&cols[(sn << 8) + (pos << 3)]) = res;
    }
    // pack + write i = 2,3
#pragma unroll
    for (int i = 0; i < 2; ++i) {
      int cbw = ((i + 2) << 3) | scb;
      uintx4 res;
#pragma unroll
      for (int jd = 0; jd < 4; ++jd) {
        float v0 = fmaf(w00, lo2f(t00[i][jd]),
                   fmaf(w01, lo2f(t01[i][jd]),
                   fmaf(w10, lo2f(t10[i][jd]), w11 * lo2f(t11[i][jd]))));
        float v1 = fmaf(w00, hi2f(t00[i][jd]),
                   fmaf(w01, hi2f(t01[i][jd]),
                   fmaf(w10, hi2f(t10[i][jd]), w11 * hi2f(t11[i][jd]))));
        res[jd] = cvtpk(v0, v1);
      }
      int pos = (cbw ^ FSWZ(sn)) & 31;
      *reinterpret_cast<uintx4*>(&cols[(sn << 8) + (pos << 3)]) = res;
    }
    __syncthreads();                     // cols(tap) published

    // prefetch i = 0,1 corners for tap+1 — in flight during the MFMA phase
    if (tap < 8) {
      const unsigned short* pn = xtb + sbase[ei + 64];
#pragma unroll
      for (int i = 0; i < 2; ++i) {
        int co = ((i << 3) | scb) << 3;
        pf00[i] = *reinterpret_cast<const uintx4*>(pn + co);
        pf01[i] = *reinterpret_cast<const uintx4*>(pn + 256 + co);
        pf10[i] = *reinterpret_cast<const uintx4*>(pn + 16384 + co);
        pf11[i] = *reinterpret_cast<const uintx4*>(pn + 16640 + co);
      }
    }

    // ---- MFMA: 8 k-steps, 2 m-tiles x 4 n-tiles per wave ----
#pragma unroll
    for (int s = 0; s < 8; ++s) {
      int ks = tap * 8 + s;
      short8 afrag[2];
#pragma unroll
      for (int a = 0; a < 2; ++a)
        afrag[a] = *reinterpret_cast<const short8*>(
            wb + (((ks * 16 + wvid * 2 + a) * 64 + lane) << 3));
      short8 bfrag[4];
#pragma unroll
      for (int u = 0; u < 4; ++u) {
        int nn = u * 16 + lm;
        int pos = ((s * 4 + q) ^ FSWZ(nn)) & 31;
        bfrag[u] = *reinterpret_cast<const short8*>(&cols[(nn << 8) + (pos << 3)]);
      }
#pragma unroll
      for (int a = 0; a < 2; ++a)
#pragma unroll
        for (int u = 0; u < 4; ++u)
          acc[a][u] = __builtin_amdgcn_mfma_f32_16x16x32_bf16(
              afrag[a], bfrag[u], acc[a][u], 0, 0, 0);
    }
    __syncthreads();                     // all reads done; next tap may write
  }

  // ---- epilogue: BN + ReLU + store ----
#pragma unroll
  for (int a = 0; a < 2; ++a) {
#pragma unroll
    for (int u = 0; u < 4; ++u) {
      int nn = u * 16 + lm;
#pragma unroll
      for (int r = 0; r < 4; ++r) {
        int o = (wvid * 2 + a) * 16 + q * 4 + r;
        float v = fmaf(acc[a][u][r], invsh[o], invsh[O + o]);
        out[((size_t)(b * O + o)) * HWSZ + h * W + nn] = fmaxf(v, 0.0f);
      }
    }
  }
}

extern "C" void kernel_launch(void* const* d_in, const int* in_sizes, int n_in,
                              void* d_out, int out_size, void* d_ws, size_t ws_size,
                              hipStream_t stream) {
  const float* x        = (const float*)d_in[0];
  const float* w_off    = (const float*)d_in[1];
  const float* b_off    = (const float*)d_in[2];
  const float* weight   = (const float*)d_in[3];
  const float* bias     = (const float*)d_in[4];
  const float* gamma    = (const float*)d_in[5];
  const float* beta     = (const float*)d_in[6];
  const float* run_mean = (const float*)d_in[7];
  const float* run_var  = (const float*)d_in[8];
  float* out = (float*)d_out;

  // workspace layout (~18.1 MB)
  char* ws = (char*)d_ws;
  unsigned short* xt = (unsigned short*)ws;                    // 16777216 B
  unsigned short* wbf = (unsigned short*)(ws + 16777216);      // 1179648 B
  unsigned short* wob = (unsigned short*)(ws + 17956864);      // 147456 B
  float* invsh = (float*)(ws + 18104320);                      // 2048 B

  prep_all<<<1349, 256, 0, stream>>>(x, weight, w_off, bias, gamma, beta,
                                     run_mean, run_var, xt, wbf, wob, invsh);
  {
    dim3 grid(NB, H);
    deform_mfma_kernel<<<grid, 512, 0, stream>>>(xt, wob, b_off, wbf, invsh, out);
  }
}

// Round 10
// 195.449 us; speedup vs baseline: 1.0738x; 1.0738x over previous
//
#include <hip/hip_runtime.h>
#include <math.h>

#define H 64
#define W 64
#define C 256
#define O 256
#define CK 2304
#define NB 8
#define HWSZ 4096            // H*W

typedef __attribute__((ext_vector_type(8))) short short8;
typedef __attribute__((ext_vector_type(4))) float floatx4;
typedef __attribute__((ext_vector_type(4))) unsigned uintx4;

// 16-slot swizzle: every 16-lane b128 phase covers all 8 bank-groups 2x (free)
#define FS(n) ((((n) & 7) << 1) | (((n) >> 3) & 1))

__device__ __forceinline__ float lo2f(unsigned u) {
  return __builtin_bit_cast(float, u << 16);
}
__device__ __forceinline__ float hi2f(unsigned u) {
  return __builtin_bit_cast(float, u & 0xffff0000u);
}
__device__ __forceinline__ unsigned pk2bf(float v0, float v1) {
  unsigned a = __builtin_bit_cast(unsigned, v0);
  unsigned b = __builtin_bit_cast(unsigned, v1);
  return ((a + 0x8000u) >> 16) | ((b + 0x8000u) & 0xffff0000u);
}
__device__ __forceinline__ unsigned cvtpk(float v0, float v1) {
#if defined(__gfx950__) && __has_builtin(__builtin_amdgcn_cvt_pk_bf16_f32)
  typedef __attribute__((ext_vector_type(2))) __bf16 bf16x2;
  bf16x2 t = __builtin_amdgcn_cvt_pk_bf16_f32(v0, v1);
  return __builtin_bit_cast(unsigned, t);
#else
  return pk2bf(v0, v1);
#endif
}

// ---------------- prep_all: transpose + weight packs + BN, ONE launch -----
__global__ __launch_bounds__(256) void prep_all(
    const float* __restrict__ x, const float* __restrict__ weight,
    const float* __restrict__ w_off, const float* __restrict__ bias,
    const float* __restrict__ gamma, const float* __restrict__ beta,
    const float* __restrict__ run_mean, const float* __restrict__ run_var,
    unsigned short* __restrict__ xt, unsigned short* __restrict__ wb,
    unsigned short* __restrict__ wob, float* __restrict__ invsh) {
  __shared__ unsigned tile[64 * 65];
  int bid = blockIdx.x;
  int tid = threadIdx.x;

  if (bid < 1024) {
    int b = bid & 7;
    int t = bid >> 3;
    int y = t >> 1;
    int cg = t & 1;
    const float* xb = x + ((size_t)b * C + cg * 128) * HWSZ + y * W;
#pragma unroll
    for (int it = 0; it < 4; ++it) {
      int e = tid + 256 * it;
      int xx4 = e & 15;
      int cp = e >> 4;
      floatx4 f0 = *reinterpret_cast<const floatx4*>(
          xb + (size_t)(2 * cp) * HWSZ + xx4 * 4);
      floatx4 f1 = *reinterpret_cast<const floatx4*>(
          xb + (size_t)(2 * cp + 1) * HWSZ + xx4 * 4);
#pragma unroll
      for (int k = 0; k < 4; ++k)
        tile[cp * 65 + xx4 * 4 + k] = cvtpk(f0[k], f1[k]);
    }
    __syncthreads();
    unsigned short* xo = xt + ((size_t)(b * 64 + y) << 14) + cg * 128;
#pragma unroll
    for (int it = 0; it < 4; ++it) {
      int e = tid + 256 * it;
      int cq = e & 15;
      int xx = e >> 4;
      unsigned u0 = tile[(cq * 4 + 0) * 65 + xx];
      unsigned u1 = tile[(cq * 4 + 1) * 65 + xx];
      unsigned u2 = tile[(cq * 4 + 2) * 65 + xx];
      unsigned u3 = tile[(cq * 4 + 3) * 65 + xx];
      uint4 v = {u0, u1, u2, u3};
      *reinterpret_cast<uint4*>(xo + (xx << 8) + (cq << 3)) = v;
    }
  } else if (bid < 1312) {
    int d0 = ((bid - 1024) * 256 + tid) * 8;
    int lane = (d0 >> 3) & 63;
    int mt = (d0 >> 9) & 15;
    int ks = d0 >> 13;
    int o = mt * 16 + (lane & 15);
    int kn0 = ks * 32 + (lane >> 4) * 8;
    int tap = kn0 >> 8;
    int c0 = kn0 & 255;
    const float* wsrc = weight + o * CK + c0 * 9 + tap;
    unsigned pk[4];
#pragma unroll
    for (int p = 0; p < 4; ++p)
      pk[p] = cvtpk(wsrc[(2 * p) * 9], wsrc[(2 * p + 1) * 9]);
    uint4 v = {pk[0], pk[1], pk[2], pk[3]};
    *reinterpret_cast<uint4*>(wb + d0) = v;
  } else if (bid < 1348) {
    int d0 = ((bid - 1312) * 256 + tid) * 8;
    int lane = (d0 >> 3) & 63;
    int mt = (d0 >> 9) & 1;
    int ks = d0 >> 10;
    int o = mt * 16 + (lane & 15);
    int kn0 = ks * 32 + (lane >> 4) * 8;
    int tap = kn0 >> 8;
    int c0 = kn0 & 255;
    uint4 v;
    if (o < 27) {
      const float* wsrc = w_off + o * CK + c0 * 9 + tap;
      unsigned pk[4];
#pragma unroll
      for (int p = 0; p < 4; ++p)
        pk[p] = cvtpk(wsrc[(2 * p) * 9], wsrc[(2 * p + 1) * 9]);
      v = (uint4){pk[0], pk[1], pk[2], pk[3]};
    } else {
      v = (uint4){0, 0, 0, 0};
    }
    *reinterpret_cast<uint4*>(wob + d0) = v;
  } else {
    int o = tid;
    float inv = gamma[o] * rsqrtf(run_var[o] + 1e-5f);
    invsh[o] = inv;
    invsh[O + o] = beta[o] + (bias[o] - run_mean[o]) * inv;
  }
}

// ---------------- Fused kernel: offset conv + deform sample + GEMM + BN ---
// grid (b, h), 512 threads (8 waves).  Block = row h: 64 px x 256 out.
// Phase B pipelined over 18 half-taps with LDS double-buffer (one barrier
// per half-tap; corner loads for ht+1 issued before MFMA(ht)).
__global__ __launch_bounds__(512, 2) void deform_mfma_kernel(
    const unsigned short* __restrict__ xt, const unsigned short* __restrict__ wob,
    const float* __restrict__ b_off, const unsigned short* __restrict__ wb,
    const float* __restrict__ invsh, float* __restrict__ out) {
  __shared__ short cols[2 * 64 * 128];   // 2 x 16 KB ping-pong, FS-swizzled
  __shared__ float sm_om[27 * 64];
  __shared__ int sbase[576];
  __shared__ float s00[576], s01[576], s10[576], s11[576];

  int tid = threadIdx.x;
  int lane = tid & 63;
  int wvid = tid >> 6;                   // 0..7
  int q = lane >> 4;
  int lm = lane & 15;
  int b = blockIdx.x;
  int h = blockIdx.y;
  const unsigned short* xtb = xt + ((size_t)b << 20);

  // ======== Phase A: offset conv, 8 waves, wave = 1 mt x 1 nt
  {
    int mt = wvid & 1;
    int nt = wvid >> 1;
    floatx4 a0 = (floatx4){0.f, 0.f, 0.f, 0.f};
    int px = nt * 16 + lm;
    for (int tap = 0; tap < 9; ++tap) {
      int yy = h - 1 + tap / 3;
      int xx = px - 1 + tap % 3;
      bool v = (yy >= 0) && (yy < H) && (xx >= 0) && (xx < W);
      const unsigned short* bp =
          xtb + ((((yy & 63) << 6) + (xx & 63)) << 8) + q * 8;
#pragma unroll
      for (int s = 0; s < 8; ++s) {
        int ks = tap * 8 + s;
        short8 bfrag;
        if (v)
          bfrag = *reinterpret_cast<const short8*>(bp + s * 32);
        else
          bfrag = (short8){0, 0, 0, 0, 0, 0, 0, 0};
        short8 afrag = *reinterpret_cast<const short8*>(
            wob + (((ks * 2 + mt) * 64 + lane) << 3));
        a0 = __builtin_amdgcn_mfma_f32_16x16x32_bf16(afrag, bfrag, a0, 0, 0, 0);
      }
    }
#pragma unroll
    for (int r = 0; r < 4; ++r) {
      int o = mt * 16 + q * 4 + r;
      if (o < 27) sm_om[o * 64 + px] = a0[r] + b_off[o];
    }
  }
  __syncthreads();

  // ======== Phase A2: separable clamp-swap bilinear tables
  for (int e = tid; e < 576; e += 512) {
    int n = e & 63;
    int k = e >> 6;
    float oy = sm_om[k * 64 + n];
    float ox = sm_om[(9 + k) * 64 + n];
    float mv = sm_om[(18 + k) * 64 + n];
    float m = 1.0f / (1.0f + __expf(-mv));
    float py = (float)(h - 1 + k / 3) + oy;
    float px = (float)(n - 1 + k % 3) + ox;
    float yf = floorf(py), xf = floorf(px);
    int y0 = (int)yf, x0 = (int)xf;
    float fy = py - yf, fx = px - xf;
    float r0, r1; int yl;
    if (y0 >= 0 && y0 <= H - 2)      { yl = y0;    r0 = 1.f - fy; r1 = fy;       }
    else if (y0 == -1)               { yl = 0;     r0 = fy;       r1 = 0.f;      }
    else if (y0 == H - 1)            { yl = H - 2; r0 = 0.f;      r1 = 1.f - fy; }
    else                             { yl = 0;     r0 = 0.f;      r1 = 0.f;      }
    float c0, c1; int xl;
    if (x0 >= 0 && x0 <= W - 2)      { xl = x0;    c0 = 1.f - fx; c1 = fx;       }
    else if (x0 == -1)               { xl = 0;     c0 = fx;       c1 = 0.f;      }
    else if (x0 == W - 1)            { xl = W - 2; c0 = 0.f;      c1 = 1.f - fx; }
    else                             { xl = 0;     c0 = 0.f;      c1 = 0.f;      }
    r0 *= m; r1 *= m;
    sbase[e] = ((yl << 6) + xl) << 8;
    s00[e] = r0 * c0; s01[e] = r0 * c1;
    s10[e] = r1 * c0; s11[e] = r1 * c1;
  }
  __syncthreads();

  // ======== Phase B: pipelined deformable GEMM over 18 half-taps
  floatx4 acc[2][4];
#pragma unroll
  for (int a = 0; a < 2; ++a)
#pragma unroll
    for (int u = 0; u < 4; ++u) acc[a][u] = (floatx4){0.f, 0.f, 0.f, 0.f};

  int sn = tid >> 3;        // pixel 0..63
  int scb = tid & 7;        // c-block low bits

  // prologue: corners for ht = 0 (tap 0, half 0)
  uintx4 pf00[2], pf01[2], pf10[2], pf11[2];
  {
    const unsigned short* p0 = xtb + sbase[sn];
#pragma unroll
    for (int i = 0; i < 2; ++i) {
      int co = ((i << 3) | scb) << 3;
      pf00[i] = *reinterpret_cast<const uintx4*>(p0 + co);
      pf01[i] = *reinterpret_cast<const uintx4*>(p0 + 256 + co);
      pf10[i] = *reinterpret_cast<const uintx4*>(p0 + 16384 + co);
      pf11[i] = *reinterpret_cast<const uintx4*>(p0 + 16640 + co);
    }
  }

  for (int ht = 0; ht < 18; ++ht) {
    int tap = ht >> 1;
    int half = ht & 1;
    int ei = tap * 64 + sn;
    float w00 = s00[ei], w01 = s01[ei], w10 = s10[ei], w11 = s11[ei];
    short* cbuf = &cols[(ht & 1) << 13];           // 64 px x 128 ch buffer

    // ---- pack + publish half-tap ht from prefetch regs ----
#pragma unroll
    for (int i = 0; i < 2; ++i) {
      uintx4 res;
#pragma unroll
      for (int jd = 0; jd < 4; ++jd) {
        float v0 = fmaf(w00, lo2f(pf00[i][jd]),
                   fmaf(w01, lo2f(pf01[i][jd]),
                   fmaf(w10, lo2f(pf10[i][jd]), w11 * lo2f(pf11[i][jd]))));
        float v1 = fmaf(w00, hi2f(pf00[i][jd]),
                   fmaf(w01, hi2f(pf01[i][jd]),
                   fmaf(w10, hi2f(pf10[i][jd]), w11 * hi2f(pf11[i][jd]))));
        res[jd] = cvtpk(v0, v1);
      }
      int cb4 = (i << 3) | scb;
      int pos = (cb4 ^ FS(sn)) & 15;
      *reinterpret_cast<uintx4*>(&cbuf[(sn << 7) + (pos << 3)]) = res;
    }
    __syncthreads();

    // ---- issue corner loads for ht+1 (latency hidden by MFMA below) ----
    if (ht < 17) {
      int htn = ht + 1;
      int tapn = htn >> 1;
      int halfn = htn & 1;
      const unsigned short* pn = xtb + sbase[tapn * 64 + sn];
#pragma unroll
      for (int i = 0; i < 2; ++i) {
        int co = ((halfn << 4) | (i << 3) | scb) << 3;
        pf00[i] = *reinterpret_cast<const uintx4*>(pn + co);
        pf01[i] = *reinterpret_cast<const uintx4*>(pn + 256 + co);
        pf10[i] = *reinterpret_cast<const uintx4*>(pn + 16384 + co);
        pf11[i] = *reinterpret_cast<const uintx4*>(pn + 16640 + co);
      }
    }

    // ---- MFMA: 4 k-steps of this half-tap ----
#pragma unroll
    for (int sl = 0; sl < 4; ++sl) {
      int s = half * 4 + sl;
      int ks = tap * 8 + s;
      short8 afrag[2];
#pragma unroll
      for (int a = 0; a < 2; ++a)
        afrag[a] = *reinterpret_cast<const short8*>(
            wb + (((ks * 16 + wvid * 2 + a) * 64 + lane) << 3));
      short8 bfrag[4];
#pragma unroll
      for (int u = 0; u < 4; ++u) {
        int nn = u * 16 + lm;
        int cb4 = (sl << 2) | q;
        int pos = (cb4 ^ FS(nn)) & 15;
        bfrag[u] = *reinterpret_cast<const short8*>(&cbuf[(nn << 7) + (pos << 3)]);
      }
#pragma unroll
      for (int a = 0; a < 2; ++a)
#pragma unroll
        for (int u = 0; u < 4; ++u)
          acc[a][u] = __builtin_amdgcn_mfma_f32_16x16x32_bf16(
              afrag[a], bfrag[u], acc[a][u], 0, 0, 0);
    }
    // no trailing barrier: next iteration writes the OTHER buffer, and the
    // barrier inside iteration ht+1 orders its writes vs our reads.
  }

  // ---- epilogue: BN + ReLU + store ----
#pragma unroll
  for (int a = 0; a < 2; ++a) {
#pragma unroll
    for (int u = 0; u < 4; ++u) {
      int nn = u * 16 + lm;
#pragma unroll
      for (int r = 0; r < 4; ++r) {
        int o = (wvid * 2 + a) * 16 + q * 4 + r;
        float v = fmaf(acc[a][u][r], invsh[o], invsh[O + o]);
        out[((size_t)(b * O + o)) * HWSZ + h * W + nn] = fmaxf(v, 0.0f);
      }
    }
  }
}

extern "C" void kernel_launch(void* const* d_in, const int* in_sizes, int n_in,
                              void* d_out, int out_size, void* d_ws, size_t ws_size,
                              hipStream_t stream) {
  const float* x        = (const float*)d_in[0];
  const float* w_off    = (const float*)d_in[1];
  const float* b_off    = (const float*)d_in[2];
  const float* weight   = (const float*)d_in[3];
  const float* bias     = (const float*)d_in[4];
  const float* gamma    = (const float*)d_in[5];
  const float* beta     = (const float*)d_in[6];
  const float* run_mean = (const float*)d_in[7];
  const float* run_var  = (const float*)d_in[8];
  float* out = (float*)d_out;

  // workspace layout (~18.1 MB)
  char* ws = (char*)d_ws;
  unsigned short* xt = (unsigned short*)ws;                    // 16777216 B
  unsigned short* wbf = (unsigned short*)(ws + 16777216);      // 1179648 B
  unsigned short* wob = (unsigned short*)(ws + 17956864);      // 147456 B
  float* invsh = (float*)(ws + 18104320);                      // 2048 B

  prep_all<<<1349, 256, 0, stream>>>(x, weight, w_off, bias, gamma, beta,
                                     run_mean, run_var, xt, wbf, wob, invsh);
  {
    dim3 grid(NB, H);
    deform_mfma_kernel<<<grid, 512, 0, stream>>>(xt, wob, b_off, wbf, invsh, out);
  }
}